// Round 1
// baseline (710.611 us; speedup 1.0000x reference)
//
#include <hip/hip_runtime.h>

typedef unsigned short u16;
typedef short bf16x8 __attribute__((ext_vector_type(8)));
typedef float f32x4 __attribute__((ext_vector_type(4)));
typedef unsigned short u16x8 __attribute__((ext_vector_type(8)));

#define LDA 40    // LDS row stride (ushorts) for K=32 tiles, b128-aligned, conflict-spread
#define LDA3 36   // G3 A-tile stride: 72B rows -> 17-dword pitch, ~conflict-free b32 column writes

static __device__ __forceinline__ u16 f2bf(float f){
  unsigned u = __builtin_bit_cast(unsigned, f);
  u += 0x7fffu + ((u >> 16) & 1u);   // RNE
  return (u16)(u >> 16);
}

union FragU { u16 h[8]; bf16x8 b; };

// ---------------- transpose + convert: dst[b][c][r] = src[b][r][c], r zero-padded to Rpad
__global__ void transpose_f32(const float* __restrict__ src, u16* __restrict__ dst,
                              int R, int C, int Rpad, long sB, long dB){
  __shared__ u16 tile[32][33];
  const int b = blockIdx.z;
  src += (long)b*sB; dst += (long)b*dB;
  const int r0 = blockIdx.x*32, c0 = blockIdx.y*32;
  const int j = threadIdx.x & 31, i0 = threadIdx.x >> 5;
  #pragma unroll
  for (int ii=0; ii<32; ii+=8){
    int r = r0+i0+ii, c = c0+j;
    u16 v = 0;
    if (r < R && c < C) v = f2bf(src[(long)r*C + c]);
    tile[i0+ii][j] = v;
  }
  __syncthreads();
  #pragma unroll
  for (int ii=0; ii<32; ii+=8){
    int c = c0+i0+ii, r = r0+j;
    if (c < C && r < Rpad) dst[(long)c*Rpad + r] = tile[j][i0+ii];
  }
}

__global__ void transpose_u16(const u16* __restrict__ src, u16* __restrict__ dst,
                              int R, int C, int Rpad, long sB, long dB){
  __shared__ u16 tile[32][33];
  const int b = blockIdx.z;
  src += (long)b*sB; dst += (long)b*dB;
  const int r0 = blockIdx.x*32, c0 = blockIdx.y*32;
  const int j = threadIdx.x & 31, i0 = threadIdx.x >> 5;
  #pragma unroll
  for (int ii=0; ii<32; ii+=8){
    int r = r0+i0+ii, c = c0+j;
    u16 v = 0;
    if (r < R && c < C) v = src[(long)r*C + c];
    tile[i0+ii][j] = v;
  }
  __syncthreads();
  #pragma unroll
  for (int ii=0; ii<32; ii+=8){
    int c = c0+i0+ii, r = r0+j;
    if (c < C && r < Rpad) dst[(long)c*Rpad + r] = tile[j][i0+ii];
  }
}

// ---------------- out[b][n][256+d] = ori[b][n][d]
__global__ void ori_copy(const float* __restrict__ ori, float* __restrict__ out){
  int idx = blockIdx.x*256 + threadIdx.x;    // 512000 float4 units
  int c4 = (idx & 63)*4;
  int row = idx >> 6;                        // b*2000+n, 0..7999
  float4 v = *(const float4*)(ori + (size_t)row*256 + c4);
  *(float4*)(out + (size_t)row*512 + 256 + c4) = v;
}

// ---------------- G1: edges[b,e,d] = sum_n H[b,e,n] * ori[b,n,d]   (M=8000,N=256,K=2048pad)
__global__ __launch_bounds__(256,2) void g1_kernel(
    const float* __restrict__ Hm, const u16* __restrict__ oriT, u16* __restrict__ edges){
  __shared__ u16 As[128*LDA];
  __shared__ u16 Bs[256*LDA];
  const int b  = blockIdx.y;
  const int bm = blockIdx.x*128;
  const int tid = threadIdx.x;
  const int w = tid>>6, lane = tid&63, quad = lane>>4, l16 = lane&15;
  const int wm = (w&1)*64, wn = (w>>1)*128;
  const float* Hb = Hm + (size_t)b*8000*2000;
  const u16*  Bg = oriT + (size_t)b*256*2048;

  f32x4 acc[4][8];
  #pragma unroll
  for (int i=0;i<4;i++)
    #pragma unroll
    for (int j=0;j<8;j++) acc[i][j] = (f32x4){0.f,0.f,0.f,0.f};

  for (int kt=0; kt<64; kt++){
    const int k0 = kt*32;
    #pragma unroll
    for (int r=0;r<4;r++){                       // A: 128x32 fp32 -> bf16 LDS
      int c = r*256 + tid;
      int row = c>>3, col4 = (c&7)*4;
      int gm = bm + row, gk = k0 + col4;
      float4 v = make_float4(0.f,0.f,0.f,0.f);
      if (gm < 8000 && gk < 2000) v = *(const float4*)(Hb + (size_t)gm*2000 + gk);
      ushort4 o; o.x=f2bf(v.x); o.y=f2bf(v.y); o.z=f2bf(v.z); o.w=f2bf(v.w);
      *(ushort4*)(As + row*LDA + col4) = o;
    }
    #pragma unroll
    for (int r=0;r<4;r++){                       // B: 256x32 bf16 (oriT zero-padded to 2048)
      int c = r*256 + tid;
      int row = c>>2, col8 = (c&3)*8;
      *(u16x8*)(Bs + row*LDA + col8) = *(const u16x8*)(Bg + (size_t)row*2048 + k0 + col8);
    }
    __syncthreads();
    bf16x8 af[4], bfr[8];
    #pragma unroll
    for (int mi=0;mi<4;mi++) af[mi] = *(const bf16x8*)(As + (wm+mi*16+l16)*LDA + quad*8);
    #pragma unroll
    for (int ni=0;ni<8;ni++) bfr[ni] = *(const bf16x8*)(Bs + (wn+ni*16+l16)*LDA + quad*8);
    #pragma unroll
    for (int mi=0;mi<4;mi++)
      #pragma unroll
      for (int ni=0;ni<8;ni++)
        acc[mi][ni] = __builtin_amdgcn_mfma_f32_16x16x32_bf16(af[mi], bfr[ni], acc[mi][ni], 0,0,0);
    __syncthreads();
  }
  #pragma unroll
  for (int mi=0;mi<4;mi++){
    #pragma unroll
    for (int r=0;r<4;r++){
      int gm = bm + wm + mi*16 + quad*4 + r;
      if (gm >= 8000) continue;
      u16* dst = edges + ((size_t)b*8000 + gm)*256;
      #pragma unroll
      for (int ni=0;ni<8;ni++){
        int gn = wn + ni*16 + l16;
        dst[gn] = f2bf(acc[mi][ni][r]);
      }
    }
  }
}

// ---------------- M1: H1[t,m,h] = relu(edges[m,:]@W1[t][:,h] + b1[t,h]) * ed[m,t]
__global__ __launch_bounds__(256,2) void m1_kernel(
    const u16* __restrict__ edges, const u16* __restrict__ W1T,
    const float* __restrict__ b1, const float* __restrict__ edist, u16* __restrict__ H1){
  __shared__ u16 As[128*LDA];
  __shared__ u16 Bs[128*LDA];
  __shared__ float eds[128];
  const int t  = blockIdx.z;
  const int bm = blockIdx.x*128;
  const int tid = threadIdx.x;
  const int w = tid>>6, lane = tid&63, quad = lane>>4, l16 = lane&15;
  const int wm = (w&1)*64, wn = (w>>1)*64;
  if (tid < 128) eds[tid] = edist[(size_t)(bm+tid)*5 + t];
  const u16* Bg = W1T + (size_t)t*128*256;

  f32x4 acc[4][4];
  #pragma unroll
  for (int i=0;i<4;i++)
    #pragma unroll
    for (int j=0;j<4;j++) acc[i][j] = (f32x4){0.f,0.f,0.f,0.f};

  for (int kt=0; kt<8; kt++){
    const int k0 = kt*32;
    #pragma unroll
    for (int r=0;r<2;r++){
      int c = r*256 + tid;
      int row = c>>2, col8 = (c&3)*8;
      *(u16x8*)(As + row*LDA + col8) = *(const u16x8*)(edges + ((size_t)(bm+row))*256 + k0+col8);
    }
    #pragma unroll
    for (int r=0;r<2;r++){
      int c = r*256 + tid;
      int row = c>>2, col8 = (c&3)*8;
      *(u16x8*)(Bs + row*LDA + col8) = *(const u16x8*)(Bg + (size_t)row*256 + k0+col8);
    }
    __syncthreads();
    bf16x8 af[4], bfr[4];
    #pragma unroll
    for (int mi=0;mi<4;mi++) af[mi] = *(const bf16x8*)(As + (wm+mi*16+l16)*LDA + quad*8);
    #pragma unroll
    for (int ni=0;ni<4;ni++) bfr[ni] = *(const bf16x8*)(Bs + (wn+ni*16+l16)*LDA + quad*8);
    #pragma unroll
    for (int mi=0;mi<4;mi++)
      #pragma unroll
      for (int ni=0;ni<4;ni++)
        acc[mi][ni] = __builtin_amdgcn_mfma_f32_16x16x32_bf16(af[mi], bfr[ni], acc[mi][ni], 0,0,0);
    __syncthreads();
  }
  #pragma unroll
  for (int mi=0;mi<4;mi++){
    #pragma unroll
    for (int r=0;r<4;r++){
      int lrow = wm + mi*16 + quad*4 + r;
      int gm = bm + lrow;
      float s = eds[lrow];
      u16* dst = H1 + ((size_t)t*32000 + gm)*128;
      #pragma unroll
      for (int ni=0;ni<4;ni++){
        int gn = wn + ni*16 + l16;
        float v = acc[mi][ni][r] + b1[t*128+gn];
        v = fmaxf(v, 0.f) * s;
        dst[gn] = f2bf(v);
      }
    }
  }
}

// ---------------- M2: EF[m,d] = sum_t (scaled h_t[m,:]) @ W2[t][:,d] + sum_t ed[m,t]*b2[t,d]
__global__ __launch_bounds__(256,2) void m2_kernel(
    const u16* __restrict__ H1, const u16* __restrict__ W2T,
    const float* __restrict__ b2, const float* __restrict__ edist, u16* __restrict__ EF){
  __shared__ u16 As[128*LDA];
  __shared__ u16 Bs[256*LDA];
  __shared__ float eds[128*5];
  __shared__ float b2s[5*256];
  const int bm = blockIdx.x*128;
  const int tid = threadIdx.x;
  const int w = tid>>6, lane = tid&63, quad = lane>>4, l16 = lane&15;
  const int wm = (w&1)*64, wn = (w>>1)*128;
  for (int i=tid;i<640;i+=256)  eds[i] = edist[(size_t)bm*5 + i];
  for (int i=tid;i<1280;i+=256) b2s[i] = b2[i];

  f32x4 acc[4][8];
  #pragma unroll
  for (int i=0;i<4;i++)
    #pragma unroll
    for (int j=0;j<8;j++) acc[i][j] = (f32x4){0.f,0.f,0.f,0.f};

  for (int kt=0; kt<20; kt++){
    const int t = kt>>2, kk0 = (kt&3)*32;
    #pragma unroll
    for (int r=0;r<2;r++){
      int c = r*256+tid; int row = c>>2, col8 = (c&3)*8;
      *(u16x8*)(As+row*LDA+col8) = *(const u16x8*)(H1 + ((size_t)t*32000 + bm+row)*128 + kk0+col8);
    }
    #pragma unroll
    for (int r=0;r<4;r++){
      int c = r*256+tid; int row = c>>2, col8 = (c&3)*8;
      *(u16x8*)(Bs+row*LDA+col8) = *(const u16x8*)(W2T + ((size_t)t*256 + row)*128 + kk0+col8);
    }
    __syncthreads();
    bf16x8 af[4], bfr[8];
    #pragma unroll
    for (int mi=0;mi<4;mi++) af[mi] = *(const bf16x8*)(As + (wm+mi*16+l16)*LDA + quad*8);
    #pragma unroll
    for (int ni=0;ni<8;ni++) bfr[ni] = *(const bf16x8*)(Bs + (wn+ni*16+l16)*LDA + quad*8);
    #pragma unroll
    for (int mi=0;mi<4;mi++)
      #pragma unroll
      for (int ni=0;ni<8;ni++)
        acc[mi][ni] = __builtin_amdgcn_mfma_f32_16x16x32_bf16(af[mi], bfr[ni], acc[mi][ni], 0,0,0);
    __syncthreads();
  }
  #pragma unroll
  for (int mi=0;mi<4;mi++){
    #pragma unroll
    for (int r=0;r<4;r++){
      int lrow = wm+mi*16+quad*4+r;
      int gm = bm+lrow;
      float e0=eds[lrow*5+0], e1=eds[lrow*5+1], e2=eds[lrow*5+2], e3=eds[lrow*5+3], e4=eds[lrow*5+4];
      u16* dst = EF + (size_t)gm*256;
      #pragma unroll
      for (int ni=0;ni<8;ni++){
        int gn = wn+ni*16+l16;
        float bias = e0*b2s[gn] + e1*b2s[256+gn] + e2*b2s[512+gn] + e3*b2s[768+gn] + e4*b2s[1024+gn];
        dst[gn] = f2bf(acc[mi][ni][r] + bias);
      }
    }
  }
}

// ---------------- G3: out[b,n,d] += sum_e H[b,e,n] * EF[b,e,d]   (TN GEMM, K split 4-way)
__global__ __launch_bounds__(256,2) void g3_kernel(
    const float* __restrict__ Hm, const u16* __restrict__ EFt, float* __restrict__ out){
  __shared__ u16 As[128*LDA3];
  __shared__ u16 Bs[256*LDA];
  const int b = blockIdx.z, ks = blockIdx.y, bm = blockIdx.x*128;
  const int tid = threadIdx.x;
  const int w = tid>>6, lane = tid&63, quad = lane>>4, l16 = lane&15;
  const int wm = (w&1)*64, wn = (w>>1)*128;
  const float* Hb = Hm + (size_t)b*8000*2000;
  const u16*  Bg = EFt + (size_t)b*256*8000;
  const int it0 = (250*ks)/4, it1 = (250*(ks+1))/4;
  const int an = tid & 127, ag = tid >> 7;
  const bool mvalid = (bm + an) < 2000;

  f32x4 acc[4][8];
  #pragma unroll
  for (int i=0;i<4;i++)
    #pragma unroll
    for (int j=0;j<8;j++) acc[i][j] = (f32x4){0.f,0.f,0.f,0.f};

  for (int kt=it0; kt<it1; kt++){
    const int k0 = kt*32;
    // A transpose-stage: As[n][k] = bf16(H[k0+k][bm+n]); lane-stride-1-row writes
    const float* src = Hb + (size_t)(k0 + ag*16)*2000 + (bm + an);
    float va[16];
    #pragma unroll
    for (int j=0;j<16;j++) va[j] = mvalid ? src[(size_t)j*2000] : 0.f;
    #pragma unroll
    for (int q=0;q<8;q++){
      unsigned pk = (unsigned)f2bf(va[2*q]) | ((unsigned)f2bf(va[2*q+1])<<16);
      *(unsigned*)(As + an*LDA3 + ag*16 + 2*q) = pk;
    }
    // B: EFt (K-contiguous)
    #pragma unroll
    for (int r=0;r<4;r++){
      int c = r*256+tid; int row = c>>2, col8=(c&3)*8;
      *(u16x8*)(Bs+row*LDA+col8) = *(const u16x8*)(Bg + (size_t)row*8000 + k0+col8);
    }
    __syncthreads();
    bf16x8 af[4], bfr[8];
    #pragma unroll
    for (int mi=0;mi<4;mi++){
      const u16* p = As + (wm+mi*16+l16)*LDA3 + quad*8;
      ushort4 lo = *(const ushort4*)(p);
      ushort4 hi = *(const ushort4*)(p+4);
      FragU fu;
      fu.h[0]=lo.x; fu.h[1]=lo.y; fu.h[2]=lo.z; fu.h[3]=lo.w;
      fu.h[4]=hi.x; fu.h[5]=hi.y; fu.h[6]=hi.z; fu.h[7]=hi.w;
      af[mi] = fu.b;
    }
    #pragma unroll
    for (int ni=0;ni<8;ni++) bfr[ni] = *(const bf16x8*)(Bs + (wn+ni*16+l16)*LDA + quad*8);
    #pragma unroll
    for (int mi=0;mi<4;mi++)
      #pragma unroll
      for (int ni=0;ni<8;ni++)
        acc[mi][ni] = __builtin_amdgcn_mfma_f32_16x16x32_bf16(af[mi], bfr[ni], acc[mi][ni], 0,0,0);
    __syncthreads();
  }
  #pragma unroll
  for (int mi=0;mi<4;mi++){
    #pragma unroll
    for (int r=0;r<4;r++){
      int gm = bm + wm + mi*16 + quad*4 + r;
      if (gm >= 2000) continue;
      float* dst = out + ((size_t)b*2000 + gm)*512;
      #pragma unroll
      for (int ni=0;ni<8;ni++){
        int gn = wn + ni*16 + l16;
        atomicAdd(dst + gn, acc[mi][ni][r]);
      }
    }
  }
}

extern "C" void kernel_launch(void* const* d_in, const int* in_sizes, int n_in,
                              void* d_out, int out_size, void* d_ws, size_t ws_size,
                              hipStream_t stream) {
  const float* ed  = (const float*)d_in[0];   // [4,8000,5]
  const float* Hm  = (const float*)d_in[1];   // [4,8000,2000]
  const float* ori = (const float*)d_in[2];   // [4,2000,256]
  const float* W1  = (const float*)d_in[3];   // [5,256,128]
  const float* b1  = (const float*)d_in[4];   // [5,128]
  const float* W2  = (const float*)d_in[5];   // [5,128,256]
  const float* b2  = (const float*)d_in[6];   // [5,256]
  float* out = (float*)d_out;                 // [4,2000,512]
  char* ws = (char*)d_ws;

  u16* oriT  = (u16*)(ws);              // 4*256*2048*2   = 4,194,304
  u16* W1T   = (u16*)(ws + 4194304);    // 5*128*256*2    =   327,680
  u16* W2T   = (u16*)(ws + 4521984);    // 5*256*128*2    =   327,680
  u16* edges = (u16*)(ws + 4849664);    // 32000*256*2    = 16,384,000
  u16* H1    = (u16*)(ws + 21233664);   // 5*32000*128*2  = 40,960,000
  u16* EF    = (u16*)(ws + 62193664);   // 32000*256*2    = 16,384,000
  u16* EFt   = (u16*)(ws + 78577664);   // 4*256*8000*2   = 16,384,000  (end 94,961,664)

  hipMemsetAsync(d_out, 0, (size_t)out_size * sizeof(float), stream);

  hipLaunchKernelGGL(transpose_f32, dim3(64,8,4), dim3(256), 0, stream,
                     ori, oriT, 2000, 256, 2048, 512000L, 524288L);
  hipLaunchKernelGGL(transpose_f32, dim3(8,4,5), dim3(256), 0, stream,
                     W1, W1T, 256, 128, 256, 32768L, 32768L);
  hipLaunchKernelGGL(transpose_f32, dim3(4,8,5), dim3(256), 0, stream,
                     W2, W2T, 128, 256, 128, 32768L, 32768L);
  hipLaunchKernelGGL(ori_copy, dim3(2000), dim3(256), 0, stream, ori, out);

  hipLaunchKernelGGL(g1_kernel, dim3(63,4), dim3(256), 0, stream, Hm, oriT, edges);
  hipLaunchKernelGGL(m1_kernel, dim3(250,1,5), dim3(256), 0, stream, edges, W1T, b1, ed, H1);
  hipLaunchKernelGGL(m2_kernel, dim3(250), dim3(256), 0, stream, H1, W2T, b2, ed, EF);
  hipLaunchKernelGGL(transpose_u16, dim3(250,8,4), dim3(256), 0, stream,
                     EF, EFt, 8000, 256, 8000, 2048000L, 2048000L);
  hipLaunchKernelGGL(g3_kernel, dim3(16,4,4), dim3(256), 0, stream, Hm, EFt, out);

  (void)in_sizes; (void)n_in; (void)ws_size;
}

// Round 2
// 659.819 us; speedup vs baseline: 1.0770x; 1.0770x over previous
//
#include <hip/hip_runtime.h>

typedef unsigned short u16;
typedef short bf16x8 __attribute__((ext_vector_type(8)));
typedef float f32x4 __attribute__((ext_vector_type(4)));
typedef unsigned short u16x8 __attribute__((ext_vector_type(8)));

#define GLL16(gp, lp) __builtin_amdgcn_global_load_lds( \
    (__attribute__((address_space(1))) const unsigned int*)(gp), \
    (__attribute__((address_space(3))) unsigned int*)(lp), 16, 0, 0)

static __device__ __forceinline__ u16 f2bf(float f){
  unsigned u = __builtin_bit_cast(unsigned, f);
  u += 0x7fffu + ((u >> 16) & 1u);   // RNE
  return (u16)(u >> 16);
}

// ---------------- prep_ht: HT[b][n][e] = bf16(H[b][e][n]); n padded to 2048 with zeros
__global__ __launch_bounds__(256) void prep_ht(const float* __restrict__ H, u16* __restrict__ HT){
  __shared__ u16 t[64*68];
  const int b = blockIdx.z;
  const int e0 = blockIdx.x*64, n0 = blockIdx.y*64;
  const float* Hb = H + (size_t)b*8000*2000;
  u16* To = HT + (size_t)b*2048*8000;
  const int tid = threadIdx.x;
  const int cg = (tid&15)*4, rb = tid>>4;
  #pragma unroll
  for (int rr=0; rr<4; rr++){
    int row = rb + rr*16;
    int gn = n0 + cg;
    float4 v = make_float4(0.f,0.f,0.f,0.f);
    if (gn < 2000) v = *(const float4*)(Hb + (size_t)(e0+row)*2000 + gn);
    ushort4 o; o.x=f2bf(v.x); o.y=f2bf(v.y); o.z=f2bf(v.z); o.w=f2bf(v.w);
    *(ushort4*)(&t[row*68 + cg]) = o;
  }
  __syncthreads();
  const int er8 = (tid&7)*8;
  #pragma unroll
  for (int rr=0; rr<2; rr++){
    int nr = (tid>>3) + rr*32;
    u16x8 v;
    #pragma unroll
    for (int j=0;j<8;j++) v[j] = t[(er8+j)*68 + nr];
    *(u16x8*)(To + (size_t)(n0+nr)*8000 + e0 + er8) = v;
  }
}

// ---------------- transpose + convert: dst[b][c][r] = bf16(src[b][r][c]), r zero-padded to Rpad
__global__ void transpose_f32(const float* __restrict__ src, u16* __restrict__ dst,
                              int R, int C, int Rpad, long sB, long dB){
  __shared__ u16 tile[32][33];
  const int b = blockIdx.z;
  src += (long)b*sB; dst += (long)b*dB;
  const int r0 = blockIdx.x*32, c0 = blockIdx.y*32;
  const int j = threadIdx.x & 31, i0 = threadIdx.x >> 5;
  #pragma unroll
  for (int ii=0; ii<32; ii+=8){
    int r = r0+i0+ii, c = c0+j;
    u16 v = 0;
    if (r < R && c < C) v = f2bf(src[(long)r*C + c]);
    tile[i0+ii][j] = v;
  }
  __syncthreads();
  #pragma unroll
  for (int ii=0; ii<32; ii+=8){
    int c = c0+i0+ii, r = r0+j;
    if (c < C && r < Rpad) dst[(long)c*Rpad + r] = tile[j][i0+ii];
  }
}

__global__ void transpose_u16(const u16* __restrict__ src, u16* __restrict__ dst,
                              int R, int C, int Rpad, long sB, long dB){
  __shared__ u16 tile[32][33];
  const int b = blockIdx.z;
  src += (long)b*sB; dst += (long)b*dB;
  const int r0 = blockIdx.x*32, c0 = blockIdx.y*32;
  const int j = threadIdx.x & 31, i0 = threadIdx.x >> 5;
  #pragma unroll
  for (int ii=0; ii<32; ii+=8){
    int r = r0+i0+ii, c = c0+j;
    u16 v = 0;
    if (r < R && c < C) v = src[(long)r*C + c];
    tile[i0+ii][j] = v;
  }
  __syncthreads();
  #pragma unroll
  for (int ii=0; ii<32; ii+=8){
    int c = c0+i0+ii, r = r0+j;
    if (c < C && r < Rpad) dst[(long)c*Rpad + r] = tile[j][i0+ii];
  }
}

// ---------------- out[b][n][0..255] = 0 ; out[b][n][256+d] = ori[b][n][d]
__global__ void ori_copy(const float* __restrict__ ori, float* __restrict__ out){
  int idx = blockIdx.x*256 + threadIdx.x;
  int c4 = (idx & 63)*4;
  int row = idx >> 6;
  float4 v = *(const float4*)(ori + (size_t)row*256 + c4);
  *(float4*)(out + (size_t)row*512 + c4) = make_float4(0.f,0.f,0.f,0.f);
  *(float4*)(out + (size_t)row*512 + 256 + c4) = v;
}

// ---------------- G1: edges[b,e,d] = sum_n H[b,e,n]*ori[b,n,d]  M=8000 N=256 K=2048pad
// 128x256 tile, fp32 A w/ register prefetch, bf16 B via global_load_lds, dbuf, 1 barrier/iter
__global__ __launch_bounds__(256,2) void g1_kernel(
    const float* __restrict__ Hm, const u16* __restrict__ oriT, u16* __restrict__ edges){
  __shared__ u16 As[2][128*32];
  __shared__ u16 Bs[2][256*32];
  const int b = blockIdx.y, bm = blockIdx.x*128;
  const int tid = threadIdx.x;
  const int w = tid>>6, quad = (tid&63)>>4, l16 = tid&15;
  const int wm = (w&1)*64, wn = (w>>1)*128;
  const float* Ab = Hm + (size_t)b*8000*2000 + (size_t)bm*2000;
  const u16*  Bb = oriT + (size_t)b*256*2048;

  float4 pa[4];
  auto loadA = [&](int kt){
    const int k0 = kt*32;
    #pragma unroll
    for (int i=0;i<4;i++){
      int idx = i*256+tid, row = idx>>3, c4 = (idx&7)*4;
      bool ok = (bm+row < 8000) && (k0+c4 < 2000);
      pa[i] = ok ? *(const float4*)(Ab + (size_t)row*2000 + k0+c4) : make_float4(0.f,0.f,0.f,0.f);
    }
  };
  auto storeA = [&](int kt){
    const int buf = kt&1;
    #pragma unroll
    for (int i=0;i<4;i++){
      int idx = i*256+tid;
      ushort4 o; o.x=f2bf(pa[i].x); o.y=f2bf(pa[i].y); o.z=f2bf(pa[i].z); o.w=f2bf(pa[i].w);
      *(ushort4*)(&As[buf][idx*4]) = o;
    }
  };
  auto stageB = [&](int kt){
    const int buf = kt&1, k0 = kt*32;
    #pragma unroll
    for (int i=0;i<4;i++){
      int idx = i*256+tid, row = idx>>2, c8 = (idx&3)*8;
      GLL16(Bb + (size_t)row*2048 + k0+c8, &Bs[buf][(i*256 + w*64)*8]);
    }
  };

  f32x4 acc[4][8];
  #pragma unroll
  for (int i=0;i<4;i++)
    #pragma unroll
    for (int j=0;j<8;j++) acc[i][j] = (f32x4){0.f,0.f,0.f,0.f};

  loadA(0); stageB(0);
  for (int kt=0; kt<64; kt++){
    storeA(kt);                      // waits pa(kt); pa loaded during prev MFMA phase
    __syncthreads();                 // Bs(kt) staged + As writes visible
    if (kt+1 < 64){ loadA(kt+1); stageB(kt+1); }   // in flight during compute
    const int buf = kt&1;
    bf16x8 af[4], bf[8];
    #pragma unroll
    for (int mi=0;mi<4;mi++) af[mi] = *(const bf16x8*)(&As[buf][(wm+mi*16+l16)*32 + quad*8]);
    #pragma unroll
    for (int ni=0;ni<8;ni++) bf[ni] = *(const bf16x8*)(&Bs[buf][(wn+ni*16+l16)*32 + quad*8]);
    #pragma unroll
    for (int mi=0;mi<4;mi++)
      #pragma unroll
      for (int ni=0;ni<8;ni++)
        acc[mi][ni] = __builtin_amdgcn_mfma_f32_16x16x32_bf16(af[mi], bf[ni], acc[mi][ni], 0,0,0);
  }
  #pragma unroll
  for (int mi=0;mi<4;mi++){
    #pragma unroll
    for (int r=0;r<4;r++){
      int gm = bm + wm + mi*16 + quad*4 + r;
      if (gm >= 8000) continue;
      u16* dst = edges + ((size_t)b*8000 + gm)*256;
      #pragma unroll
      for (int ni=0;ni<8;ni++) dst[wn + ni*16 + l16] = f2bf(acc[mi][ni][r]);
    }
  }
}

// ---------------- M1: H1[t,m,h] = relu(edges[m,:]@W1T[t][h,:] + b1) * ed[m,t]
__global__ __launch_bounds__(256,2) void m1_kernel(
    const u16* __restrict__ edges, const u16* __restrict__ W1T,
    const float* __restrict__ b1, const float* __restrict__ edist, u16* __restrict__ H1){
  __shared__ u16 As[2][128*32];
  __shared__ u16 Bs[2][128*32];
  __shared__ float eds[128], b1s[128];
  const int t = blockIdx.y, bm = blockIdx.x*128;
  const int tid = threadIdx.x;
  const int w = tid>>6, quad = (tid&63)>>4, l16 = tid&15;
  const int wm = (w&1)*64, wn = (w>>1)*64;
  if (tid < 128){ eds[tid] = edist[(size_t)(bm+tid)*5 + t]; b1s[tid] = b1[t*128+tid]; }
  const u16* Ab = edges + (size_t)bm*256;
  const u16* Bb = W1T + (size_t)t*128*256;

  auto stage = [&](int kt){
    const int buf = kt&1, k0 = kt*32;
    #pragma unroll
    for (int i=0;i<2;i++){
      int idx = i*256+tid, row = idx>>2, c8 = (idx&3)*8;
      GLL16(Ab + (size_t)row*256 + k0+c8, &As[buf][(i*256 + w*64)*8]);
      GLL16(Bb + (size_t)row*256 + k0+c8, &Bs[buf][(i*256 + w*64)*8]);
    }
  };

  f32x4 acc[4][4];
  #pragma unroll
  for (int i=0;i<4;i++)
    #pragma unroll
    for (int j=0;j<4;j++) acc[i][j] = (f32x4){0.f,0.f,0.f,0.f};

  stage(0);
  for (int kt=0; kt<8; kt++){
    __syncthreads();
    if (kt+1 < 8) stage(kt+1);
    const int buf = kt&1;
    bf16x8 af[4], bf[4];
    #pragma unroll
    for (int mi=0;mi<4;mi++) af[mi] = *(const bf16x8*)(&As[buf][(wm+mi*16+l16)*32 + quad*8]);
    #pragma unroll
    for (int ni=0;ni<4;ni++) bf[ni] = *(const bf16x8*)(&Bs[buf][(wn+ni*16+l16)*32 + quad*8]);
    #pragma unroll
    for (int mi=0;mi<4;mi++)
      #pragma unroll
      for (int ni=0;ni<4;ni++)
        acc[mi][ni] = __builtin_amdgcn_mfma_f32_16x16x32_bf16(af[mi], bf[ni], acc[mi][ni], 0,0,0);
  }
  #pragma unroll
  for (int mi=0;mi<4;mi++){
    #pragma unroll
    for (int r=0;r<4;r++){
      int lrow = wm + mi*16 + quad*4 + r;
      float s = eds[lrow];
      u16* dst = H1 + ((size_t)t*32000 + bm + lrow)*128;
      #pragma unroll
      for (int ni=0;ni<4;ni++){
        int lc = wn + ni*16 + l16;
        float v = fmaxf(acc[mi][ni][r] + b1s[lc], 0.f) * s;
        dst[lc] = f2bf(v);
      }
    }
  }
}

// ---------------- M2: EF[m,d] = sum_{t,h} H1[t,m,h]*W2T[t][d,h] + sum_t ed[m,t]*b2[t,d]
__global__ __launch_bounds__(256,2) void m2_kernel(
    const u16* __restrict__ H1, const u16* __restrict__ W2T,
    const float* __restrict__ b2, const float* __restrict__ edist, u16* __restrict__ EF){
  __shared__ u16 As[2][128*32];
  __shared__ u16 Bs[2][128*32];
  __shared__ float eds[640], b2s[640];
  const int bm = blockIdx.x*128, bn = blockIdx.y*128;
  const int tid = threadIdx.x;
  const int w = tid>>6, quad = (tid&63)>>4, l16 = tid&15;
  const int wm = (w&1)*64, wn = (w>>1)*64;
  for (int i=tid;i<640;i+=256){
    eds[i] = edist[(size_t)bm*5 + i];
    b2s[i] = b2[(i>>7)*256 + bn + (i&127)];
  }
  auto stage = [&](int kt){
    const int buf = kt&1, t = kt>>2, k0 = (kt&3)*32;
    #pragma unroll
    for (int i=0;i<2;i++){
      int idx = i*256+tid, row = idx>>2, c8 = (idx&3)*8;
      GLL16(H1 + ((size_t)t*32000 + bm+row)*128 + k0+c8, &As[buf][(i*256 + w*64)*8]);
      GLL16(W2T + ((size_t)t*256 + bn+row)*128 + k0+c8, &Bs[buf][(i*256 + w*64)*8]);
    }
  };

  f32x4 acc[4][4];
  #pragma unroll
  for (int i=0;i<4;i++)
    #pragma unroll
    for (int j=0;j<4;j++) acc[i][j] = (f32x4){0.f,0.f,0.f,0.f};

  stage(0);
  for (int kt=0; kt<20; kt++){
    __syncthreads();
    if (kt+1 < 20) stage(kt+1);
    const int buf = kt&1;
    bf16x8 af[4], bf[4];
    #pragma unroll
    for (int mi=0;mi<4;mi++) af[mi] = *(const bf16x8*)(&As[buf][(wm+mi*16+l16)*32 + quad*8]);
    #pragma unroll
    for (int ni=0;ni<4;ni++) bf[ni] = *(const bf16x8*)(&Bs[buf][(wn+ni*16+l16)*32 + quad*8]);
    #pragma unroll
    for (int mi=0;mi<4;mi++)
      #pragma unroll
      for (int ni=0;ni<4;ni++)
        acc[mi][ni] = __builtin_amdgcn_mfma_f32_16x16x32_bf16(af[mi], bf[ni], acc[mi][ni], 0,0,0);
  }
  #pragma unroll
  for (int mi=0;mi<4;mi++){
    #pragma unroll
    for (int r=0;r<4;r++){
      int lrow = wm + mi*16 + quad*4 + r;
      float e0=eds[lrow*5+0], e1=eds[lrow*5+1], e2=eds[lrow*5+2], e3=eds[lrow*5+3], e4=eds[lrow*5+4];
      u16* dst = EF + (size_t)(bm+lrow)*256 + bn;
      #pragma unroll
      for (int ni=0;ni<4;ni++){
        int lc = wn + ni*16 + l16;
        float bias = e0*b2s[lc] + e1*b2s[128+lc] + e2*b2s[256+lc] + e3*b2s[384+lc] + e4*b2s[512+lc];
        dst[lc] = f2bf(acc[mi][ni][r] + bias);
      }
    }
  }
}

// ---------------- G3: out[b,n,d] += sum_e HT[b,n,e]*EFt[b,d,e]  M=2048 N=256 K=8000, ksplit 8
__global__ __launch_bounds__(256,2) void g3_kernel(
    const u16* __restrict__ HT, const u16* __restrict__ EFt, float* __restrict__ out){
  __shared__ u16 As[2][128*32];
  __shared__ u16 Bs[2][256*32];
  const int bm = blockIdx.x*128, ks = blockIdx.y, b = blockIdx.z;
  const int tid = threadIdx.x;
  const int w = tid>>6, quad = (tid&63)>>4, l16 = tid&15;
  const int wm = (w&1)*64, wn = (w>>1)*128;
  const u16* Ab = HT + (size_t)b*2048*8000 + (size_t)bm*8000;
  const u16* Bb = EFt + (size_t)b*256*8000;
  const int it0 = (250*ks)/8, it1 = (250*(ks+1))/8;

  auto stage = [&](int kt){
    const int buf = kt&1, k0 = kt*32;
    #pragma unroll
    for (int i=0;i<2;i++){
      int idx = i*256+tid, row = idx>>2, c8 = (idx&3)*8;
      GLL16(Ab + (size_t)row*8000 + k0+c8, &As[buf][(i*256 + w*64)*8]);
    }
    #pragma unroll
    for (int i=0;i<4;i++){
      int idx = i*256+tid, row = idx>>2, c8 = (idx&3)*8;
      GLL16(Bb + (size_t)row*8000 + k0+c8, &Bs[buf][(i*256 + w*64)*8]);
    }
  };

  f32x4 acc[4][8];
  #pragma unroll
  for (int i=0;i<4;i++)
    #pragma unroll
    for (int j=0;j<8;j++) acc[i][j] = (f32x4){0.f,0.f,0.f,0.f};

  stage(it0);
  for (int kt=it0; kt<it1; kt++){
    __syncthreads();
    if (kt+1 < it1) stage(kt+1);
    const int buf = kt&1;
    bf16x8 af[4], bf[8];
    #pragma unroll
    for (int mi=0;mi<4;mi++) af[mi] = *(const bf16x8*)(&As[buf][(wm+mi*16+l16)*32 + quad*8]);
    #pragma unroll
    for (int ni=0;ni<8;ni++) bf[ni] = *(const bf16x8*)(&Bs[buf][(wn+ni*16+l16)*32 + quad*8]);
    #pragma unroll
    for (int mi=0;mi<4;mi++)
      #pragma unroll
      for (int ni=0;ni<8;ni++)
        acc[mi][ni] = __builtin_amdgcn_mfma_f32_16x16x32_bf16(af[mi], bf[ni], acc[mi][ni], 0,0,0);
  }
  #pragma unroll
  for (int mi=0;mi<4;mi++){
    #pragma unroll
    for (int r=0;r<4;r++){
      int gm = bm + wm + mi*16 + quad*4 + r;
      if (gm >= 2000) continue;
      float* dst = out + ((size_t)b*2000 + gm)*512;
      #pragma unroll
      for (int ni=0;ni<8;ni++) atomicAdd(dst + wn + ni*16 + l16, acc[mi][ni][r]);
    }
  }
}

extern "C" void kernel_launch(void* const* d_in, const int* in_sizes, int n_in,
                              void* d_out, int out_size, void* d_ws, size_t ws_size,
                              hipStream_t stream) {
  const float* ed  = (const float*)d_in[0];   // [4,8000,5]
  const float* Hm  = (const float*)d_in[1];   // [4,8000,2000]
  const float* ori = (const float*)d_in[2];   // [4,2000,256]
  const float* W1  = (const float*)d_in[3];   // [5,256,128]
  const float* b1  = (const float*)d_in[4];   // [5,128]
  const float* W2  = (const float*)d_in[5];   // [5,128,256]
  const float* b2  = (const float*)d_in[6];   // [5,256]
  float* out = (float*)d_out;                 // [4,2000,512]
  char* ws = (char*)d_ws;

  u16* HT    = (u16*)(ws);                 // 4*2048*8000*2 = 131,072,000
  u16* oriT  = (u16*)(ws + 131072000);     // 4*256*2048*2  =   4,194,304
  u16* W1T   = (u16*)(ws + 135266304);     // 5*128*256*2   =     327,680
  u16* W2T   = (u16*)(ws + 135593984);     // 5*256*128*2   =     327,680
  u16* edges = (u16*)(ws + 135921664);     // 32000*256*2   =  16,384,000  (reused as EFt)
  u16* H1    = (u16*)(ws + 152305664);     // 5*32000*128*2 =  40,960,000
  u16* EF    = (u16*)(ws + 193265664);     // 32000*256*2   =  16,384,000  (end ~209.6 MB)
  u16* EFt   = edges;                      // alias: edges dead after m1

  hipLaunchKernelGGL(prep_ht, dim3(125,32,4), dim3(256), 0, stream, Hm, HT);
  hipLaunchKernelGGL(transpose_f32, dim3(64,8,4), dim3(256), 0, stream,
                     ori, oriT, 2000, 256, 2048, 512000L, 524288L);
  hipLaunchKernelGGL(transpose_f32, dim3(8,4,5), dim3(256), 0, stream,
                     W1, W1T, 256, 128, 256, 32768L, 32768L);
  hipLaunchKernelGGL(transpose_f32, dim3(4,8,5), dim3(256), 0, stream,
                     W2, W2T, 128, 256, 128, 32768L, 32768L);
  hipLaunchKernelGGL(ori_copy, dim3(2000), dim3(256), 0, stream, ori, out);

  hipLaunchKernelGGL(g1_kernel, dim3(63,4), dim3(256), 0, stream, Hm, oriT, edges);
  hipLaunchKernelGGL(m1_kernel, dim3(250,5), dim3(256), 0, stream, edges, W1T, b1, ed, H1);
  hipLaunchKernelGGL(m2_kernel, dim3(250,2), dim3(256), 0, stream, H1, W2T, b2, ed, EF);
  hipLaunchKernelGGL(transpose_u16, dim3(250,8,4), dim3(256), 0, stream,
                     EF, EFt, 8000, 256, 8000, 2048000L, 2048000L);
  hipLaunchKernelGGL(g3_kernel, dim3(16,8,4), dim3(256), 0, stream, HT, EFt, out);

  (void)in_sizes; (void)n_in; (void)ws_size;
}

// Round 3
// 586.435 us; speedup vs baseline: 1.2117x; 1.1251x over previous
//
#include <hip/hip_runtime.h>

typedef unsigned short u16;
typedef short bf16x8 __attribute__((ext_vector_type(8)));
typedef float f32x4 __attribute__((ext_vector_type(4)));
typedef unsigned short u16x8 __attribute__((ext_vector_type(8)));

#define GLL16(gp, lp) __builtin_amdgcn_global_load_lds( \
    (__attribute__((address_space(1))) const unsigned int*)(gp), \
    (__attribute__((address_space(3))) unsigned int*)(lp), 16, 0, 0)

static __device__ __forceinline__ u16 f2bf(float f){
  unsigned u = __builtin_bit_cast(unsigned, f);
  u += 0x7fffu + ((u >> 16) & 1u);   // RNE
  return (u16)(u >> 16);
}

// ---------------- transpose + convert: dst[b][c][r] = bf16(src[b][r][c]), r zero-padded to Rpad
__global__ void transpose_f32(const float* __restrict__ src, u16* __restrict__ dst,
                              int R, int C, int Rpad, long sB, long dB){
  __shared__ u16 tile[32][33];
  const int b = blockIdx.z;
  src += (long)b*sB; dst += (long)b*dB;
  const int r0 = blockIdx.x*32, c0 = blockIdx.y*32;
  const int j = threadIdx.x & 31, i0 = threadIdx.x >> 5;
  #pragma unroll
  for (int ii=0; ii<32; ii+=8){
    int r = r0+i0+ii, c = c0+j;
    u16 v = 0;
    if (r < R && c < C) v = f2bf(src[(long)r*C + c]);
    tile[i0+ii][j] = v;
  }
  __syncthreads();
  #pragma unroll
  for (int ii=0; ii<32; ii+=8){
    int c = c0+i0+ii, r = r0+j;
    if (c < C && r < Rpad) dst[(long)c*Rpad + r] = tile[j][i0+ii];
  }
}

__global__ void transpose_u16(const u16* __restrict__ src, u16* __restrict__ dst,
                              int R, int C, int Rpad, long sB, long dB){
  __shared__ u16 tile[32][33];
  const int b = blockIdx.z;
  src += (long)b*sB; dst += (long)b*dB;
  const int r0 = blockIdx.x*32, c0 = blockIdx.y*32;
  const int j = threadIdx.x & 31, i0 = threadIdx.x >> 5;
  #pragma unroll
  for (int ii=0; ii<32; ii+=8){
    int r = r0+i0+ii, c = c0+j;
    u16 v = 0;
    if (r < R && c < C) v = src[(long)r*C + c];
    tile[i0+ii][j] = v;
  }
  __syncthreads();
  #pragma unroll
  for (int ii=0; ii<32; ii+=8){
    int c = c0+i0+ii, r = r0+j;
    if (c < C && r < Rpad) dst[(long)c*Rpad + r] = tile[j][i0+ii];
  }
}

// ---------------- G1: edges[b,e,d] = sum_n H[b,e,n]*ori[b,n,d]  M=8000 N=256 K=2048pad
// Also emits HT[b][n][e] = bf16(H[b][e][n]) via k-major LDS staging (replaces prep_ht).
__global__ __launch_bounds__(256,2) void g1_kernel(
    const float* __restrict__ Hm, const u16* __restrict__ oriT,
    u16* __restrict__ edges, u16* __restrict__ HT){
  __shared__ u16 As[2][128*32];
  __shared__ u16 Bs[2][256*32];
  __shared__ u16 At[2][32*136];      // k-major copy for transposed HT write; 272B row pitch
  const int b = blockIdx.y, bm = blockIdx.x*128;
  const int tid = threadIdx.x;
  const int w = tid>>6, quad = (tid&63)>>4, l16 = tid&15;
  const int wm = (w&1)*64, wn = (w>>1)*128;
  const float* Ab = Hm + (size_t)b*8000*2000 + (size_t)bm*2000;
  const u16*  Bb = oriT + (size_t)b*256*2048;
  u16* HTb = HT + (size_t)b*2048*8000;

  float4 pa[4];
  auto loadA = [&](int kt){
    const int k0 = kt*32;
    #pragma unroll
    for (int i=0;i<4;i++){
      int idx = i*256+tid, row = idx>>3, c4 = (idx&7)*4;
      bool ok = (bm+row < 8000) && (k0+c4 < 2000);
      pa[i] = ok ? *(const float4*)(Ab + (size_t)row*2000 + k0+c4) : make_float4(0.f,0.f,0.f,0.f);
    }
  };
  auto storeA = [&](int kt){
    const int buf = kt&1;
    #pragma unroll
    for (int i=0;i<4;i++){
      int idx = i*256+tid, row = idx>>3, c4 = (idx&7)*4;
      ushort4 o; o.x=f2bf(pa[i].x); o.y=f2bf(pa[i].y); o.z=f2bf(pa[i].z); o.w=f2bf(pa[i].w);
      *(ushort4*)(&As[buf][idx*4]) = o;
      At[buf][(c4+0)*136 + row] = o.x;
      At[buf][(c4+1)*136 + row] = o.y;
      At[buf][(c4+2)*136 + row] = o.z;
      At[buf][(c4+3)*136 + row] = o.w;
    }
  };
  auto stageB = [&](int kt){
    const int buf = kt&1, k0 = kt*32;
    #pragma unroll
    for (int i=0;i<4;i++){
      int idx = i*256+tid;
      int row = idx>>2, c8 = (idx&3)*8;
      GLL16(Bb + (size_t)row*2048 + k0+c8, &Bs[buf][(i*256 + w*64)*8]);
    }
  };

  f32x4 acc[4][8];
  #pragma unroll
  for (int i=0;i<4;i++)
    #pragma unroll
    for (int j=0;j<8;j++) acc[i][j] = (f32x4){0.f,0.f,0.f,0.f};

  loadA(0); stageB(0);
  for (int kt=0; kt<64; kt++){
    storeA(kt);
    __syncthreads();
    if (kt+1 < 64){ loadA(kt+1); stageB(kt+1); }
    const int buf = kt&1, k0 = kt*32;
    // HT write: 32(k) x 128(m) tile, coalesced 16B stores
    #pragma unroll
    for (int j2=0;j2<2;j2++){
      int ci = j2*256 + tid;
      int kk = ci>>4, c = ci&15, m0 = c*8;
      if (bm + m0 < 8000){
        u16x8 v = *(const u16x8*)(&At[buf][kk*136 + m0]);
        *(u16x8*)(HTb + (size_t)(k0+kk)*8000 + bm + m0) = v;
      }
    }
    bf16x8 af[4], bf[8];
    #pragma unroll
    for (int mi=0;mi<4;mi++) af[mi] = *(const bf16x8*)(&As[buf][(wm+mi*16+l16)*32 + quad*8]);
    #pragma unroll
    for (int ni=0;ni<8;ni++) bf[ni] = *(const bf16x8*)(&Bs[buf][(wn+ni*16+l16)*32 + quad*8]);
    #pragma unroll
    for (int mi=0;mi<4;mi++)
      #pragma unroll
      for (int ni=0;ni<8;ni++)
        acc[mi][ni] = __builtin_amdgcn_mfma_f32_16x16x32_bf16(af[mi], bf[ni], acc[mi][ni], 0,0,0);
  }
  #pragma unroll
  for (int mi=0;mi<4;mi++){
    #pragma unroll
    for (int r=0;r<4;r++){
      int gm = bm + wm + mi*16 + quad*4 + r;
      if (gm >= 8000) continue;
      u16* dst = edges + ((size_t)b*8000 + gm)*256;
      #pragma unroll
      for (int ni=0;ni<8;ni++) dst[wn + ni*16 + l16] = f2bf(acc[mi][ni][r]);
    }
  }
}

// ---------------- M1: H1[t,m,h] = relu(edges[m,:]@W1T[t][h,:] + b1) * ed[m,t]
__global__ __launch_bounds__(256,2) void m1_kernel(
    const u16* __restrict__ edges, const u16* __restrict__ W1T,
    const float* __restrict__ b1, const float* __restrict__ edist, u16* __restrict__ H1){
  __shared__ u16 As[2][128*32];
  __shared__ u16 Bs[2][128*32];
  __shared__ float eds[128], b1s[128];
  const int t = blockIdx.y, bm = blockIdx.x*128;
  const int tid = threadIdx.x;
  const int w = tid>>6, quad = (tid&63)>>4, l16 = tid&15;
  const int wm = (w&1)*64, wn = (w>>1)*64;
  if (tid < 128){ eds[tid] = edist[(size_t)(bm+tid)*5 + t]; b1s[tid] = b1[t*128+tid]; }
  const u16* Ab = edges + (size_t)bm*256;
  const u16* Bb = W1T + (size_t)t*128*256;

  auto stage = [&](int kt){
    const int buf = kt&1, k0 = kt*32;
    #pragma unroll
    for (int i=0;i<2;i++){
      int idx = i*256+tid, row = idx>>2, c8 = (idx&3)*8;
      GLL16(Ab + (size_t)row*256 + k0+c8, &As[buf][(i*256 + w*64)*8]);
      GLL16(Bb + (size_t)row*256 + k0+c8, &Bs[buf][(i*256 + w*64)*8]);
    }
  };

  f32x4 acc[4][4];
  #pragma unroll
  for (int i=0;i<4;i++)
    #pragma unroll
    for (int j=0;j<4;j++) acc[i][j] = (f32x4){0.f,0.f,0.f,0.f};

  stage(0);
  for (int kt=0; kt<8; kt++){
    __syncthreads();
    if (kt+1 < 8) stage(kt+1);
    const int buf = kt&1;
    bf16x8 af[4], bf[4];
    #pragma unroll
    for (int mi=0;mi<4;mi++) af[mi] = *(const bf16x8*)(&As[buf][(wm+mi*16+l16)*32 + quad*8]);
    #pragma unroll
    for (int ni=0;ni<4;ni++) bf[ni] = *(const bf16x8*)(&Bs[buf][(wn+ni*16+l16)*32 + quad*8]);
    #pragma unroll
    for (int mi=0;mi<4;mi++)
      #pragma unroll
      for (int ni=0;ni<4;ni++)
        acc[mi][ni] = __builtin_amdgcn_mfma_f32_16x16x32_bf16(af[mi], bf[ni], acc[mi][ni], 0,0,0);
  }
  #pragma unroll
  for (int mi=0;mi<4;mi++){
    #pragma unroll
    for (int r=0;r<4;r++){
      int lrow = wm + mi*16 + quad*4 + r;
      float s = eds[lrow];
      u16* dst = H1 + ((size_t)t*32000 + bm + lrow)*128;
      #pragma unroll
      for (int ni=0;ni<4;ni++){
        int lc = wn + ni*16 + l16;
        float v = fmaxf(acc[mi][ni][r] + b1s[lc], 0.f) * s;
        dst[lc] = f2bf(v);
      }
    }
  }
}

// ---------------- M2: EF[m,d] = sum_{t,h} H1[t,m,h]*W2T[t][d,h] + sum_t ed[m,t]*b2[t,d]
__global__ __launch_bounds__(256,2) void m2_kernel(
    const u16* __restrict__ H1, const u16* __restrict__ W2T,
    const float* __restrict__ b2, const float* __restrict__ edist, u16* __restrict__ EF){
  __shared__ u16 As[2][128*32];
  __shared__ u16 Bs[2][128*32];
  __shared__ float eds[640], b2s[640];
  const int bm = blockIdx.x*128, bn = blockIdx.y*128;
  const int tid = threadIdx.x;
  const int w = tid>>6, quad = (tid&63)>>4, l16 = tid&15;
  const int wm = (w&1)*64, wn = (w>>1)*64;
  for (int i=tid;i<640;i+=256){
    eds[i] = edist[(size_t)bm*5 + i];
    b2s[i] = b2[(i>>7)*256 + bn + (i&127)];
  }
  auto stage = [&](int kt){
    const int buf = kt&1, t = kt>>2, k0 = (kt&3)*32;
    #pragma unroll
    for (int i=0;i<2;i++){
      int idx = i*256+tid, row = idx>>2, c8 = (idx&3)*8;
      GLL16(H1 + ((size_t)t*32000 + bm+row)*128 + k0+c8, &As[buf][(i*256 + w*64)*8]);
      GLL16(W2T + ((size_t)t*256 + bn+row)*128 + k0+c8, &Bs[buf][(i*256 + w*64)*8]);
    }
  };

  f32x4 acc[4][4];
  #pragma unroll
  for (int i=0;i<4;i++)
    #pragma unroll
    for (int j=0;j<4;j++) acc[i][j] = (f32x4){0.f,0.f,0.f,0.f};

  stage(0);
  for (int kt=0; kt<20; kt++){
    __syncthreads();
    if (kt+1 < 20) stage(kt+1);
    const int buf = kt&1;
    bf16x8 af[4], bf[4];
    #pragma unroll
    for (int mi=0;mi<4;mi++) af[mi] = *(const bf16x8*)(&As[buf][(wm+mi*16+l16)*32 + quad*8]);
    #pragma unroll
    for (int ni=0;ni<4;ni++) bf[ni] = *(const bf16x8*)(&Bs[buf][(wn+ni*16+l16)*32 + quad*8]);
    #pragma unroll
    for (int mi=0;mi<4;mi++)
      #pragma unroll
      for (int ni=0;ni<4;ni++)
        acc[mi][ni] = __builtin_amdgcn_mfma_f32_16x16x32_bf16(af[mi], bf[ni], acc[mi][ni], 0,0,0);
  }
  #pragma unroll
  for (int mi=0;mi<4;mi++){
    #pragma unroll
    for (int r=0;r<4;r++){
      int lrow = wm + mi*16 + quad*4 + r;
      float e0=eds[lrow*5+0], e1=eds[lrow*5+1], e2=eds[lrow*5+2], e3=eds[lrow*5+3], e4=eds[lrow*5+4];
      u16* dst = EF + (size_t)(bm+lrow)*256 + bn;
      #pragma unroll
      for (int ni=0;ni<4;ni++){
        int lc = wn + ni*16 + l16;
        float bias = e0*b2s[lc] + e1*b2s[128+lc] + e2*b2s[256+lc] + e3*b2s[384+lc] + e4*b2s[512+lc];
        dst[lc] = f2bf(acc[mi][ni][r] + bias);
      }
    }
  }
}

// ---------------- G3: part[ks][b,m,d] = sum_{e in slice} HT[b,m,e]*EFt[b,d,e]  (no atomics)
__global__ __launch_bounds__(256,2) void g3_kernel(
    const u16* __restrict__ HT, const u16* __restrict__ EFt, float* __restrict__ part){
  __shared__ u16 As[2][128*32];
  __shared__ u16 Bs[2][256*32];
  const int bm = blockIdx.x*128, ks = blockIdx.y, b = blockIdx.z;
  const int tid = threadIdx.x;
  const int w = tid>>6, quad = (tid&63)>>4, l16 = tid&15;
  const int wm = (w&1)*64, wn = (w>>1)*128;
  const u16* Ab = HT + (size_t)b*2048*8000 + (size_t)bm*8000;
  const u16* Bb = EFt + (size_t)b*256*8000;
  const int it0 = (250*ks)/4, it1 = (250*(ks+1))/4;

  auto stage = [&](int kt){
    const int buf = kt&1, k0 = kt*32;
    #pragma unroll
    for (int i=0;i<2;i++){
      int idx = i*256+tid, row = idx>>2, c8 = (idx&3)*8;
      GLL16(Ab + (size_t)row*8000 + k0+c8, &As[buf][(i*256 + w*64)*8]);
    }
    #pragma unroll
    for (int i=0;i<4;i++){
      int idx = i*256+tid, row = idx>>2, c8 = (idx&3)*8;
      GLL16(Bb + (size_t)row*8000 + k0+c8, &Bs[buf][(i*256 + w*64)*8]);
    }
  };

  f32x4 acc[4][8];
  #pragma unroll
  for (int i=0;i<4;i++)
    #pragma unroll
    for (int j=0;j<8;j++) acc[i][j] = (f32x4){0.f,0.f,0.f,0.f};

  stage(it0);
  for (int kt=it0; kt<it1; kt++){
    __syncthreads();
    if (kt+1 < it1) stage(kt+1);
    const int buf = kt&1;
    bf16x8 af[4], bf[8];
    #pragma unroll
    for (int mi=0;mi<4;mi++) af[mi] = *(const bf16x8*)(&As[buf][(wm+mi*16+l16)*32 + quad*8]);
    #pragma unroll
    for (int ni=0;ni<8;ni++) bf[ni] = *(const bf16x8*)(&Bs[buf][(wn+ni*16+l16)*32 + quad*8]);
    #pragma unroll
    for (int mi=0;mi<4;mi++)
      #pragma unroll
      for (int ni=0;ni<8;ni++)
        acc[mi][ni] = __builtin_amdgcn_mfma_f32_16x16x32_bf16(af[mi], bf[ni], acc[mi][ni], 0,0,0);
  }
  float* dst0 = part + ((size_t)(b*4 + ks)*2048)*256;
  #pragma unroll
  for (int mi=0;mi<4;mi++){
    #pragma unroll
    for (int r=0;r<4;r++){
      int gm = bm + wm + mi*16 + quad*4 + r;
      float* dst = dst0 + (size_t)gm*256;
      #pragma unroll
      for (int ni=0;ni<8;ni++) dst[wn + ni*16 + l16] = acc[mi][ni][r];
    }
  }
}

// ---------------- assemble: out[b,n,:256] = sum_ks part ; out[b,n,256:] = ori[b,n,:]
__global__ void assemble_kernel(const float* __restrict__ part, const float* __restrict__ ori,
                                float* __restrict__ out){
  const int b = blockIdx.y;
  int u = blockIdx.x*256 + threadIdx.x;          // 500*256 = 128000 = 2000*64
  int n = u>>6, c4 = (u&63)*4;
  f32x4 s = (f32x4){0.f,0.f,0.f,0.f};
  #pragma unroll
  for (int ks=0; ks<4; ks++)
    s += *(const f32x4*)(part + ((size_t)(b*4+ks)*2048 + n)*256 + c4);
  float* dst = out + ((size_t)(b*2000+n))*512;
  *(f32x4*)(dst + c4) = s;
  *(f32x4*)(dst + 256 + c4) = *(const f32x4*)(ori + ((size_t)(b*2000+n))*256 + c4);
}

extern "C" void kernel_launch(void* const* d_in, const int* in_sizes, int n_in,
                              void* d_out, int out_size, void* d_ws, size_t ws_size,
                              hipStream_t stream) {
  const float* ed  = (const float*)d_in[0];   // [4,8000,5]
  const float* Hm  = (const float*)d_in[1];   // [4,8000,2000]
  const float* ori = (const float*)d_in[2];   // [4,2000,256]
  const float* W1  = (const float*)d_in[3];   // [5,256,128]
  const float* b1  = (const float*)d_in[4];   // [5,128]
  const float* W2  = (const float*)d_in[5];   // [5,128,256]
  const float* b2  = (const float*)d_in[6];   // [5,256]
  float* out = (float*)d_out;                 // [4,2000,512]
  char* ws = (char*)d_ws;

  u16* HT    = (u16*)(ws);                 // 4*2048*8000*2 = 131,072,000
  u16* oriT  = (u16*)(ws + 131072000);     // 4*256*2048*2  =   4,194,304
  u16* W1T   = (u16*)(ws + 135266304);     // 5*128*256*2   =     327,680
  u16* W2T   = (u16*)(ws + 135593984);     // 5*256*128*2   =     327,680
  u16* edges = (u16*)(ws + 135921664);     // 32000*256*2   =  16,384,000  (reused as EFt)
  u16* H1    = (u16*)(ws + 152305664);     // 5*32000*128*2 =  40,960,000  (reused as part)
  u16* EF    = (u16*)(ws + 193265664);     // 32000*256*2   =  16,384,000  (end ~209.6 MB)
  u16* EFt   = edges;                      // alias: edges dead after m1
  float* part = (float*)H1;                // alias: H1 dead after m2 (33.5 MB <= 41 MB)

  hipLaunchKernelGGL(transpose_f32, dim3(64,8,4), dim3(256), 0, stream,
                     ori, oriT, 2000, 256, 2048, 512000L, 524288L);
  hipLaunchKernelGGL(transpose_f32, dim3(8,4,5), dim3(256), 0, stream,
                     W1, W1T, 256, 128, 256, 32768L, 32768L);
  hipLaunchKernelGGL(transpose_f32, dim3(4,8,5), dim3(256), 0, stream,
                     W2, W2T, 128, 256, 128, 32768L, 32768L);

  hipLaunchKernelGGL(g1_kernel, dim3(63,4), dim3(256), 0, stream, Hm, oriT, edges, HT);
  hipLaunchKernelGGL(m1_kernel, dim3(250,5), dim3(256), 0, stream, edges, W1T, b1, ed, H1);
  hipLaunchKernelGGL(m2_kernel, dim3(250,2), dim3(256), 0, stream, H1, W2T, b2, ed, EF);
  hipLaunchKernelGGL(transpose_u16, dim3(250,8,4), dim3(256), 0, stream,
                     EF, EFt, 8000, 256, 8000, 2048000L, 2048000L);
  hipLaunchKernelGGL(g3_kernel, dim3(16,4,4), dim3(256), 0, stream, HT, EFt, part);
  hipLaunchKernelGGL(assemble_kernel, dim3(500,4), dim3(256), 0, stream, part, ori, out);

  (void)in_sizes; (void)n_in; (void)ws_size;
}